// Round 2
// baseline (721.825 us; speedup 1.0000x reference)
//
#include <hip/hip_runtime.h>
#include <stdint.h>

#define SEQ 2048
#define DM  4096
#define DH  128
#define NH  32
#define LDQ 6144   // q(4096) + k(1024) + v(1024)

typedef __attribute__((ext_vector_type(8))) short bf16x8;
typedef __attribute__((ext_vector_type(4))) float fx4;
typedef __attribute__((ext_vector_type(4))) unsigned short u16x4;

__device__ __forceinline__ unsigned short f2bf(float f){
  union { float f; unsigned u; } x; x.f = f;
  unsigned r = x.u + 0x7fffu + ((x.u >> 16) & 1u);
  return (unsigned short)(r >> 16);
}
__device__ __forceinline__ float bf2f(unsigned short u){
  union { unsigned u; float f; } x; x.u = ((unsigned)u) << 16; return x.f;
}
__device__ __forceinline__ void gload16(const void* g, void* l){
  __builtin_amdgcn_global_load_lds((const __attribute__((address_space(1))) void*)g,
                                   (__attribute__((address_space(3))) void*)l, 16, 0, 0);
}

// ---------------- fp32 -> bf16 weight convert ----------------
__global__ __launch_bounds__(256) void cvt_f32_bf16(const float* __restrict__ src,
                                                    unsigned short* __restrict__ dst, int n4){
  int i = blockIdx.x * 256 + threadIdx.x;
  if (i >= n4) return;
  float4 v = ((const float4*)src)[i];
  u16x4 o;
  o[0] = f2bf(v.x); o[1] = f2bf(v.y); o[2] = f2bf(v.z); o[3] = f2bf(v.w);
  ((u16x4*)dst)[i] = o;
}

// ---------------- RMSNorm (fp32 in, bf16 out) ----------------
__global__ __launch_bounds__(256) void rmsnorm_bf16(const float* __restrict__ x,
                                                    const float* __restrict__ w,
                                                    unsigned short* __restrict__ h){
  int row = blockIdx.x, t = threadIdx.x;
  const float4* xr = (const float4*)(x + (size_t)row * DM);
  float4 v[4];
  float ss = 0.f;
#pragma unroll
  for (int i = 0; i < 4; i++){
    v[i] = xr[t + i * 256];
    ss += v[i].x*v[i].x + v[i].y*v[i].y + v[i].z*v[i].z + v[i].w*v[i].w;
  }
#pragma unroll
  for (int o = 32; o > 0; o >>= 1) ss += __shfl_xor(ss, o, 64);
  __shared__ float red[4];
  if ((t & 63) == 0) red[t >> 6] = ss;
  __syncthreads();
  float tot = red[0] + red[1] + red[2] + red[3];
  float rc = rsqrtf(tot * (1.f / DM) + 1e-5f);
  const float4* wr = (const float4*)w;
  unsigned short* hr = h + (size_t)row * DM;
#pragma unroll
  for (int i = 0; i < 4; i++){
    float4 wv = wr[t + i * 256];
    u16x4 o;
    o[0] = f2bf(v[i].x * rc * wv.x);
    o[1] = f2bf(v[i].y * rc * wv.y);
    o[2] = f2bf(v[i].z * rc * wv.z);
    o[3] = f2bf(v[i].w * rc * wv.w);
    ((u16x4*)hr)[t + i * 256] = o;
  }
}

// ---------------- GEMM: C[M][ldc] = A[M][K] * B[N][K]^T  (m97 structure) ----------------
// OUT_F32=0: bf16 out.  OUT_F32=1: fp32 out + residual add.
template<int OUT_F32>
__global__ __launch_bounds__(256) void gemm_bt(const unsigned short* __restrict__ A,
                                               const unsigned short* __restrict__ B,
                                               void* __restrict__ Cout,
                                               const float* __restrict__ residual,
                                               int K, int ldc){
  __shared__ unsigned short As[128 * 32];
  __shared__ unsigned short Bs[128 * 32];
  int tid = threadIdx.x, lane = tid & 63, w = tid >> 6;
  int bn = blockIdx.x, bm = blockIdx.y;
  int wr = w >> 1, wc = w & 1;          // 2x2 wave grid, each wave 64x64
  fx4 acc[4][4] = {};
  const char* Abase = (const char*)(A + (size_t)(bm * 128) * K);
  const char* Bbase = (const char*)(B + (size_t)(bn * 128) * K);
  int o0 = tid * 16, o1 = o0 + 4096;
  int r0 = o0 >> 6, c0 = o0 & 63;
  int r1 = o1 >> 6, c1 = o1 & 63;
  int lr = lane & 15, lk = (lane >> 4) << 4;

  for (int k0 = 0; k0 < K; k0 += 32){
    const char* ab = Abase + (size_t)k0 * 2;
    const char* bb = Bbase + (size_t)k0 * 2;
    gload16(ab + (size_t)r0 * (K * 2) + c0, (char*)As + o0);
    gload16(ab + (size_t)r1 * (K * 2) + c1, (char*)As + o1);
    gload16(bb + (size_t)r0 * (K * 2) + c0, (char*)Bs + o0);
    gload16(bb + (size_t)r1 * (K * 2) + c1, (char*)Bs + o1);
    __syncthreads();
    bf16x8 af[4], bfr[4];
#pragma unroll
    for (int m = 0; m < 4; m++)
      af[m] = *(const bf16x8*)((const char*)As + (wr * 64 + m * 16 + lr) * 64 + lk);
#pragma unroll
    for (int n = 0; n < 4; n++)
      bfr[n] = *(const bf16x8*)((const char*)Bs + (wc * 64 + n * 16 + lr) * 64 + lk);
#pragma unroll
    for (int m = 0; m < 4; m++)
#pragma unroll
      for (int n = 0; n < 4; n++)
        acc[m][n] = __builtin_amdgcn_mfma_f32_16x16x32_bf16(af[m], bfr[n], acc[m][n], 0, 0, 0);
    __syncthreads();
  }
  int lg = lane >> 4;
#pragma unroll
  for (int m = 0; m < 4; m++){
    int row0 = bm * 128 + wr * 64 + m * 16 + lg * 4;
#pragma unroll
    for (int n = 0; n < 4; n++){
      int col = bn * 128 + wc * 64 + n * 16 + lr;
#pragma unroll
      for (int jr = 0; jr < 4; jr++){
        size_t idx = (size_t)(row0 + jr) * ldc + col;
        if (OUT_F32) ((float*)Cout)[idx] = residual[idx] + acc[m][n][jr];
        else         ((unsigned short*)Cout)[idx] = f2bf(acc[m][n][jr]);
      }
    }
  }
}

// ---------------- RoPE in-place on q,k columns of qkv (bf16) ----------------
__global__ __launch_bounds__(256) void rope_qk(unsigned short* __restrict__ qkv,
                                               const float* __restrict__ rc,
                                               const float* __restrict__ rs){
  int s = blockIdx.y;
  int cp = blockIdx.x * 256 + threadIdx.x;   // pair index 0..2559 (q:0..2047, k:2048..2559)
  int col = cp * 2;
  int d = col & 127;
  float c  = rc[s * 128 + d];
  float sn = rs[s * 128 + d];
  unsigned* p = (unsigned*)(qkv + (size_t)s * LDQ + col);
  unsigned xv = *p;
  float x0 = bf2f((unsigned short)(xv & 0xffff));
  float x1 = bf2f((unsigned short)(xv >> 16));
  float y0 = x0 * c - x1 * sn;
  float y1 = x1 * c + x0 * sn;
  *p = (unsigned)f2bf(y0) | ((unsigned)f2bf(y1) << 16);
}

// ---------------- Flash attention (causal, GQA 4:1) ----------------
// block = 4 waves; each wave owns 16 q rows; 32-key tiles.
// S^T = mfma(K_frag(sigma-permuted rows), Q_frag)  ->  D-layout == PV A-layout.
__global__ __launch_bounds__(256) void attn_fwd(const unsigned short* __restrict__ qkv,
                                                unsigned short* __restrict__ aout){
  __shared__ unsigned short Ks[32 * 128];
  __shared__ unsigned short Vs[32 * 128];   // subtiled: [d16][k4][4][16]
  int tid = threadIdx.x, lane = tid & 63, w = tid >> 6;
  int h = blockIdx.x >> 5, qt = blockIdx.x & 31;
  int kvh = h >> 2;
  int qbase = qt * 64 + w * 16;
  int lr = lane & 15, lg = lane >> 4;

  // Q fragments (B-operand of swapped QK^T): lane holds Q[q=lr][d=ks*32+lg*8+j]
  bf16x8 qf[4];
  const unsigned short* qrow = qkv + (size_t)(qbase + lr) * LDQ + h * DH;
#pragma unroll
  for (int ks = 0; ks < 4; ks++)
    qf[ks] = *(const bf16x8*)(qrow + ks * 32 + lg * 8);

  fx4 acc_o[8] = {};
  float mrun = -1e30f, lrun = 0.f;
  const float scale = 0.08838834764831845f;  // 1/sqrt(128)
  int nkt = (qt + 1) * 2;
  int o0 = tid * 16, o1 = o0 + 4096;

  for (int kt = 0; kt < nkt; kt++){
    int kb = kt * 32;
    {
      // K tile: linear LDS [32][128], XOR-swizzled source (rule #21)
      int r0 = o0 >> 8, c0 = (o0 & 255) ^ ((r0 & 7) << 4);
      int r1 = o1 >> 8, c1 = (o1 & 255) ^ ((r1 & 7) << 4);
      const char* kbase = (const char*)(qkv + (size_t)kb * LDQ + 4096 + kvh * DH);
      gload16(kbase + (size_t)r0 * (LDQ * 2) + c0, (char*)Ks + o0);
      gload16(kbase + (size_t)r1 * (LDQ * 2) + c1, (char*)Ks + o1);
      // V tile: subtiled dest, permuted source. e: d16=e>>9, k4=(e>>6)&7, kr=(e>>4)&3, c=e&15
      const char* vbase = (const char*)(qkv + (size_t)kb * LDQ + 5120 + kvh * DH);
      int e0 = o0 >> 1;
      int key0 = (((e0 >> 6) & 7) << 2) + ((e0 >> 4) & 3);
      int cc0  = ((e0 >> 9) << 4) + (e0 & 15);
      gload16(vbase + (size_t)key0 * (LDQ * 2) + cc0 * 2, (char*)Vs + o0);
      int e1 = o1 >> 1;
      int key1 = (((e1 >> 6) & 7) << 2) + ((e1 >> 4) & 3);
      int cc1  = ((e1 >> 9) << 4) + (e1 & 15);
      gload16(vbase + (size_t)key1 * (LDQ * 2) + cc1 * 2, (char*)Vs + o1);
    }
    __syncthreads();

    // S^T: lane holds S[q=lr][key = kb + lg*8 + jr + 4*hh]
    fx4 st[2];
#pragma unroll
    for (int hh = 0; hh < 2; hh++){
      fx4 a = {};
      int krow = lr + 4 * (lr >> 2) + 4 * hh;      // sigma_hh(lr)
      int xr = (krow & 7) << 4;
#pragma unroll
      for (int ks = 0; ks < 4; ks++){
        int colb = ks * 64 + (lg << 4);
        bf16x8 kf = *(const bf16x8*)((const char*)Ks + krow * 256 + (colb ^ xr));
        a = __builtin_amdgcn_mfma_f32_16x16x32_bf16(kf, qf[ks], a, 0, 0, 0);
      }
      st[hh] = a;
    }

    // online softmax (state per q=lr, replicated over lg)
    int qg = qbase + lr;
    float p[2][4];
    float tmax = -1e30f;
#pragma unroll
    for (int hh = 0; hh < 2; hh++)
#pragma unroll
      for (int jr = 0; jr < 4; jr++){
        int kg = kb + lg * 8 + jr + 4 * hh;
        float sv = (kg <= qg) ? st[hh][jr] * scale : -1e30f;
        p[hh][jr] = sv;
        tmax = fmaxf(tmax, sv);
      }
    tmax = fmaxf(tmax, __shfl_xor(tmax, 16, 64));
    tmax = fmaxf(tmax, __shfl_xor(tmax, 32, 64));
    float mnew = fmaxf(mrun, tmax);
    float corr = __expf(mrun - mnew);
    float psum = 0.f;
#pragma unroll
    for (int hh = 0; hh < 2; hh++)
#pragma unroll
      for (int jr = 0; jr < 4; jr++){
        float e = __expf(p[hh][jr] - mnew);
        p[hh][jr] = e;
        psum += e;
      }
    psum += __shfl_xor(psum, 16, 64);
    psum += __shfl_xor(psum, 32, 64);
    lrun = lrun * corr + psum;
    mrun = mnew;

    // rescale O (O rows are q' = lg*4+jr -> fetch per-row corr via shuffle)
    float corr4[4];
#pragma unroll
    for (int jr = 0; jr < 4; jr++) corr4[jr] = __shfl(corr, lg * 4 + jr, 64);
#pragma unroll
    for (int d0 = 0; d0 < 8; d0++)
#pragma unroll
      for (int jr = 0; jr < 4; jr++) acc_o[d0][jr] *= corr4[jr];

    // P fragment: A-operand elem j=jr+4*hh holds P[q=lr][key=lg*8+j]
    union { bf16x8 v; unsigned short s[8]; } pf;
#pragma unroll
    for (int hh = 0; hh < 2; hh++)
#pragma unroll
      for (int jr = 0; jr < 4; jr++) pf.s[jr + 4 * hh] = f2bf(p[hh][jr]);

    // PV: B-frag j: V[key=lg*8+j][col=d0*16+lr] from subtiled Vs
#pragma unroll
    for (int d0 = 0; d0 < 8; d0++){
      union { bf16x8 v; unsigned short s[8]; } bv;
#pragma unroll
      for (int j = 0; j < 8; j++)
        bv.s[j] = Vs[d0 * 512 + lg * 128 + ((j >> 2) << 6) + ((j & 3) << 4) + lr];
      acc_o[d0] = __builtin_amdgcn_mfma_f32_16x16x32_bf16(pf.v, bv.v, acc_o[d0], 0, 0, 0);
    }
    __syncthreads();
  }

  // epilogue: normalize by 1/l and store bf16
  float linv = 1.f / lrun;
  float inv4[4];
#pragma unroll
  for (int jr = 0; jr < 4; jr++) inv4[jr] = __shfl(linv, lg * 4 + jr, 64);
  unsigned short* orow = aout + (size_t)qbase * DM + h * DH;
#pragma unroll
  for (int d0 = 0; d0 < 8; d0++)
#pragma unroll
    for (int jr = 0; jr < 4; jr++){
      int qq = lg * 4 + jr;
      orow[(size_t)qq * DM + d0 * 16 + lr] = f2bf(acc_o[d0][jr] * inv4[jr]);
    }
}

// ---------------- launch ----------------
extern "C" void kernel_launch(void* const* d_in, const int* in_sizes, int n_in,
                              void* d_out, int out_size, void* d_ws, size_t ws_size,
                              hipStream_t stream){
  const float* x  = (const float*)d_in[0];
  const float* rc = (const float*)d_in[1];
  const float* rs = (const float*)d_in[2];
  // d_in[3] = mask (causal tril; implemented in-kernel)
  const float* nw = (const float*)d_in[4];
  const float* wq = (const float*)d_in[5];
  const float* wk = (const float*)d_in[6];
  const float* wv = (const float*)d_in[7];
  const float* wo = (const float*)d_in[8];
  float* out = (float*)d_out;
  char* ws = (char*)d_ws;

  unsigned short* h_bf = (unsigned short*)(ws);                 // 2048*4096*2 = 16,777,216
  unsigned short* qkv  = (unsigned short*)(ws + 16777216ull);   // 2048*6144*2 = 25,165,824
  unsigned short* a_bf = (unsigned short*)(ws + 41943040ull);   // 16,777,216
  unsigned short* Wqkv = (unsigned short*)(ws + 58720256ull);   // 6144*4096*2 = 50,331,648
  unsigned short* Wo   = (unsigned short*)(ws + 109051904ull);  // 33,554,432  (end ~142.6MB)

  cvt_f32_bf16<<<16384, 256, 0, stream>>>(wq, Wqkv, 4194304);
  cvt_f32_bf16<<<4096, 256, 0, stream>>>(wk, Wqkv + 16777216, 1048576);
  cvt_f32_bf16<<<4096, 256, 0, stream>>>(wv, Wqkv + 20971520, 1048576);
  cvt_f32_bf16<<<16384, 256, 0, stream>>>(wo, Wo, 4194304);
  rmsnorm_bf16<<<2048, 256, 0, stream>>>(x, nw, h_bf);
  gemm_bt<0><<<dim3(48, 16), 256, 0, stream>>>(h_bf, Wqkv, qkv, nullptr, 4096, 6144);
  rope_qk<<<dim3(10, 2048), 256, 0, stream>>>(qkv, rc, rs);
  attn_fwd<<<1024, 256, 0, stream>>>(qkv, a_bf);
  gemm_bt<1><<<dim3(32, 16), 256, 0, stream>>>(a_bf, Wo, out, x, 4096, 4096);
}

// Round 3
// 569.997 us; speedup vs baseline: 1.2664x; 1.2664x over previous
//
#include <hip/hip_runtime.h>
#include <stdint.h>

#define SEQ 2048
#define DM  4096
#define DH  128
#define NH  32
#define LDQ 5120   // q(4096) + k(1024); V goes to Vt

typedef __attribute__((ext_vector_type(8))) short bf16x8;
typedef __attribute__((ext_vector_type(4))) float fx4;
typedef __attribute__((ext_vector_type(4))) unsigned short u16x4;

__device__ __forceinline__ unsigned short f2bf(float f){
  union { float f; unsigned u; } x; x.f = f;
  unsigned r = x.u + 0x7fffu + ((x.u >> 16) & 1u);
  return (unsigned short)(r >> 16);
}
__device__ __forceinline__ float bf2f(unsigned short u){
  union { unsigned u; float f; } x; x.u = ((unsigned)u) << 16; return x.f;
}
__device__ __forceinline__ void gload16(const void* g, void* l){
  __builtin_amdgcn_global_load_lds((const __attribute__((address_space(1))) void*)g,
                                   (__attribute__((address_space(3))) void*)l, 16, 0, 0);
}

// ---------------- fp32 -> bf16 weight convert ----------------
__global__ __launch_bounds__(256) void cvt_f32_bf16(const float* __restrict__ src,
                                                    unsigned short* __restrict__ dst, int n4){
  int i = blockIdx.x * 256 + threadIdx.x;
  if (i >= n4) return;
  float4 v = ((const float4*)src)[i];
  u16x4 o;
  o[0] = f2bf(v.x); o[1] = f2bf(v.y); o[2] = f2bf(v.z); o[3] = f2bf(v.w);
  ((u16x4*)dst)[i] = o;
}

// ---------------- RMSNorm (fp32 in, bf16 out) ----------------
__global__ __launch_bounds__(256) void rmsnorm_bf16(const float* __restrict__ x,
                                                    const float* __restrict__ w,
                                                    unsigned short* __restrict__ h){
  int row = blockIdx.x, t = threadIdx.x;
  const float4* xr = (const float4*)(x + (size_t)row * DM);
  float4 v[4];
  float ss = 0.f;
#pragma unroll
  for (int i = 0; i < 4; i++){
    v[i] = xr[t + i * 256];
    ss += v[i].x*v[i].x + v[i].y*v[i].y + v[i].z*v[i].z + v[i].w*v[i].w;
  }
#pragma unroll
  for (int o = 32; o > 0; o >>= 1) ss += __shfl_xor(ss, o, 64);
  __shared__ float red[4];
  if ((t & 63) == 0) red[t >> 6] = ss;
  __syncthreads();
  float tot = red[0] + red[1] + red[2] + red[3];
  float rc = rsqrtf(tot * (1.f / DM) + 1e-5f);
  const float4* wr = (const float4*)w;
  unsigned short* hr = h + (size_t)row * DM;
#pragma unroll
  for (int i = 0; i < 4; i++){
    float4 wv = wr[t + i * 256];
    u16x4 o;
    o[0] = f2bf(v[i].x * rc * wv.x);
    o[1] = f2bf(v[i].y * rc * wv.y);
    o[2] = f2bf(v[i].z * rc * wv.z);
    o[3] = f2bf(v[i].w * rc * wv.w);
    ((u16x4*)hr)[t + i * 256] = o;
  }
}

// ---------------- GEMM: C[M][ldc] = A[M][K] * B[N][K]^T  (m97 structure) ----------------
// MODE 1: fp32 out + residual add.
// MODE 2: bf16 out to C for cols<5120; cols>=5120 (V) redirected transposed to vt[col-5120][row].
template<int MODE>
__global__ __launch_bounds__(256) void gemm_bt(const unsigned short* __restrict__ A,
                                               const unsigned short* __restrict__ B,
                                               void* __restrict__ Cout,
                                               const float* __restrict__ residual,
                                               unsigned short* __restrict__ vtp,
                                               int K, int ldc){
  __shared__ unsigned short As[128 * 32];
  __shared__ unsigned short Bs[128 * 32];
  int tid = threadIdx.x, lane = tid & 63, w = tid >> 6;
  int bn = blockIdx.x, bm = blockIdx.y;
  int wr = w >> 1, wc = w & 1;          // 2x2 wave grid, each wave 64x64
  fx4 acc[4][4] = {};
  const char* Abase = (const char*)(A + (size_t)(bm * 128) * K);
  const char* Bbase = (const char*)(B + (size_t)(bn * 128) * K);
  int o0 = tid * 16, o1 = o0 + 4096;
  int r0 = o0 >> 6, c0 = o0 & 63;
  int r1 = o1 >> 6, c1 = o1 & 63;
  int lr = lane & 15, lk = (lane >> 4) << 4;

  for (int k0 = 0; k0 < K; k0 += 32){
    const char* ab = Abase + (size_t)k0 * 2;
    const char* bb = Bbase + (size_t)k0 * 2;
    gload16(ab + (size_t)r0 * (K * 2) + c0, (char*)As + o0);
    gload16(ab + (size_t)r1 * (K * 2) + c1, (char*)As + o1);
    gload16(bb + (size_t)r0 * (K * 2) + c0, (char*)Bs + o0);
    gload16(bb + (size_t)r1 * (K * 2) + c1, (char*)Bs + o1);
    __syncthreads();
    bf16x8 af[4], bfr[4];
#pragma unroll
    for (int m = 0; m < 4; m++)
      af[m] = *(const bf16x8*)((const char*)As + (wr * 64 + m * 16 + lr) * 64 + lk);
#pragma unroll
    for (int n = 0; n < 4; n++)
      bfr[n] = *(const bf16x8*)((const char*)Bs + (wc * 64 + n * 16 + lr) * 64 + lk);
#pragma unroll
    for (int m = 0; m < 4; m++)
#pragma unroll
      for (int n = 0; n < 4; n++)
        acc[m][n] = __builtin_amdgcn_mfma_f32_16x16x32_bf16(af[m], bfr[n], acc[m][n], 0, 0, 0);
    __syncthreads();
  }
  int lg = lane >> 4;
#pragma unroll
  for (int m = 0; m < 4; m++){
    int row0 = bm * 128 + wr * 64 + m * 16 + lg * 4;
#pragma unroll
    for (int n = 0; n < 4; n++){
      int col = bn * 128 + wc * 64 + n * 16 + lr;
      if (MODE == 2 && bn >= 40){
        // V columns: store transposed bf16 to vt[col-5120][row] (jr-contiguous)
        int vtcol = col - 5120;
        u16x4 o4;
#pragma unroll
        for (int jr = 0; jr < 4; jr++) o4[jr] = f2bf(acc[m][n][jr]);
        *(u16x4*)(vtp + (size_t)vtcol * SEQ + row0) = o4;
      } else {
#pragma unroll
        for (int jr = 0; jr < 4; jr++){
          size_t idx = (size_t)(row0 + jr) * ldc + col;
          if (MODE == 1) ((float*)Cout)[idx] = residual[idx] + acc[m][n][jr];
          else           ((unsigned short*)Cout)[idx] = f2bf(acc[m][n][jr]);
        }
      }
    }
  }
}

// ---------------- RoPE in-place on q,k columns of qkv (bf16) ----------------
__global__ __launch_bounds__(256) void rope_qk(unsigned short* __restrict__ qkv,
                                               const float* __restrict__ rc,
                                               const float* __restrict__ rs){
  int s = blockIdx.y;
  int cp = blockIdx.x * 256 + threadIdx.x;   // pair index 0..2559 (q:0..2047, k:2048..2559)
  int col = cp * 2;
  int d = col & 127;
  float c  = rc[s * 128 + d];
  float sn = rs[s * 128 + d];
  unsigned* p = (unsigned*)(qkv + (size_t)s * LDQ + col);
  unsigned xv = *p;
  float x0 = bf2f((unsigned short)(xv & 0xffff));
  float x1 = bf2f((unsigned short)(xv >> 16));
  float y0 = x0 * c - x1 * sn;
  float y1 = x1 * c + x0 * sn;
  *p = (unsigned)f2bf(y0) | ((unsigned)f2bf(y1) << 16);
}

// ---------------- Flash attention (causal, GQA 4:1) ----------------
// block = 4 waves x 32 q-rows each (128 q/block); KVBLK=64.
// S^T = mfma(K_perm, Q);  O^T = mfma(Vt, P^T)  [pf registers serve as B-operand directly].
__global__ __launch_bounds__(256) void attn_fwd(const unsigned short* __restrict__ qkv,
                                                const unsigned short* __restrict__ vt,
                                                unsigned short* __restrict__ aout){
  __shared__ unsigned short Ks[64 * 128];   // [key][d], rows 256B, col ^= perm(row)<<4
  __shared__ unsigned short Vts[128 * 64];  // [d][key], rows 128B, col ^= (d&7)<<4
  int tid = threadIdx.x, lane = tid & 63, w = tid >> 6;
  int bid = blockIdx.x;
  int qt = 15 - (bid >> 5);                 // heavy blocks first
  int h = bid & 31, kvh = h >> 2;
  int qbase = qt * 128 + w * 32;
  int lr = lane & 15, lg = lane >> 4;
  const float scale = 0.08838834764831845f; // 1/sqrt(128)

  // Q fragments: qf[qh][ks] : lane holds Q[q=qbase+qh*16+lr][d=ks*32+lg*8+j]
  bf16x8 qf[2][4];
#pragma unroll
  for (int qh = 0; qh < 2; qh++){
    const unsigned short* qrow = qkv + (size_t)(qbase + qh * 16 + lr) * LDQ + h * DH;
#pragma unroll
    for (int ks = 0; ks < 4; ks++)
      qf[qh][ks] = *(const bf16x8*)(qrow + ks * 32 + lg * 8);
  }

  fx4 acc[2][8] = {};
  float mrun[2] = {-1e30f, -1e30f}, lrun[2] = {0.f, 0.f};
  int nkt = 2 * (qt + 1);

  for (int kt = 0; kt < nkt; kt++){
    int kb = kt * 64;
    // ---- stage K (16KB) and Vt (16KB), swizzled source / linear dest ----
    const char* kgb = (const char*)(qkv + (size_t)kb * LDQ + 4096 + kvh * DH);
#pragma unroll
    for (int i = 0; i < 4; i++){
      int o = tid * 16 + i * 4096;
      int r = o >> 8;
      int cb = (o & 255) ^ ((((r & 3) | (((r >> 3) & 1) << 2))) << 4);
      gload16(kgb + (size_t)r * (LDQ * 2) + cb, (char*)Ks + o);
    }
#pragma unroll
    for (int i = 0; i < 4; i++){
      int o = tid * 16 + i * 4096;
      int d = o >> 7;
      int cb = (o & 127) ^ ((d & 7) << 4);
      gload16((const char*)vt + ((size_t)(kvh * 128 + d) * SEQ + kb) * 2 + cb, (char*)Vts + o);
    }
    __syncthreads();

    // ---- QK^T: st[qh][hh][jr] = S[q=qbase+qh*16+lr][key=kb+32*(hh>>1)+lg*8+4*(hh&1)+jr]
    fx4 st[2][4] = {};
#pragma unroll
    for (int hh = 0; hh < 4; hh++){
      int krow = 32 * (hh >> 1) + lr + 4 * (lr >> 2) + 4 * (hh & 1);
      int xr = ((krow & 3) | (((krow >> 3) & 1) << 2)) << 4;
      bf16x8 kf[4];
#pragma unroll
      for (int ks = 0; ks < 4; ks++)
        kf[ks] = *(const bf16x8*)((const char*)Ks + krow * 256 + ((ks * 64 + lg * 16) ^ xr));
#pragma unroll
      for (int qh = 0; qh < 2; qh++)
#pragma unroll
        for (int ks = 0; ks < 4; ks++)
          st[qh][hh] = __builtin_amdgcn_mfma_f32_16x16x32_bf16(kf[ks], qf[qh][ks], st[qh][hh], 0, 0, 0);
    }

    // ---- online softmax (state per q=lr, replicated over lg) + P fragments ----
    union { bf16x8 v; unsigned short s[8]; } pf[2][2];
#pragma unroll
    for (int qh = 0; qh < 2; qh++){
      int qg = qbase + qh * 16 + lr;
      float p[4][4];
      float tmax = -1e30f;
#pragma unroll
      for (int hh = 0; hh < 4; hh++)
#pragma unroll
        for (int jr = 0; jr < 4; jr++){
          int kg = kb + 32 * (hh >> 1) + lg * 8 + 4 * (hh & 1) + jr;
          float sv = (kg <= qg) ? st[qh][hh][jr] * scale : -1e30f;
          p[hh][jr] = sv;
          tmax = fmaxf(tmax, sv);
        }
      tmax = fmaxf(tmax, __shfl_xor(tmax, 16, 64));
      tmax = fmaxf(tmax, __shfl_xor(tmax, 32, 64));
      float mnew = fmaxf(mrun[qh], tmax);
      float corr = __expf(mrun[qh] - mnew);
      float psum = 0.f;
#pragma unroll
      for (int hh = 0; hh < 4; hh++)
#pragma unroll
        for (int jr = 0; jr < 4; jr++){
          float e = __expf(p[hh][jr] - mnew);
          p[hh][jr] = e;
          psum += e;
        }
      psum += __shfl_xor(psum, 16, 64);
      psum += __shfl_xor(psum, 32, 64);
      lrun[qh] = lrun[qh] * corr + psum;
      mrun[qh] = mnew;
      // pf[qh][c].s[j] = P[q][32c + lg*8 + j]
#pragma unroll
      for (int j = 0; j < 8; j++){
        pf[qh][0].s[j] = f2bf(p[(j >> 2)][j & 3]);
        pf[qh][1].s[j] = f2bf(p[2 + (j >> 2)][j & 3]);
      }
      // rescale O^T (col = q = lr -> per-lane scalar, no shuffles)
#pragma unroll
      for (int d0 = 0; d0 < 8; d0++)
#pragma unroll
        for (int jr = 0; jr < 4; jr++) acc[qh][d0][jr] *= corr;
    }

    // ---- PV: O^T[d][q] += Vt_frag * pf ----
#pragma unroll
    for (int d0 = 0; d0 < 8; d0++){
      int vrow = d0 * 16 + lr;
      int xv = (lr & 7) << 4;
      bf16x8 va0 = *(const bf16x8*)((const char*)Vts + vrow * 128 + ((lg * 16) ^ xv));
      bf16x8 va1 = *(const bf16x8*)((const char*)Vts + vrow * 128 + ((64 + lg * 16) ^ xv));
#pragma unroll
      for (int qh = 0; qh < 2; qh++){
        acc[qh][d0] = __builtin_amdgcn_mfma_f32_16x16x32_bf16(va0, pf[qh][0].v, acc[qh][d0], 0, 0, 0);
        acc[qh][d0] = __builtin_amdgcn_mfma_f32_16x16x32_bf16(va1, pf[qh][1].v, acc[qh][d0], 0, 0, 0);
      }
    }
    __syncthreads();
  }

  // ---- epilogue: O[q][d] = acc^T / l ----
#pragma unroll
  for (int qh = 0; qh < 2; qh++){
    float linv = 1.f / lrun[qh];
    unsigned short* orow = aout + (size_t)(qbase + qh * 16 + lr) * DM + h * DH;
#pragma unroll
    for (int d0 = 0; d0 < 8; d0++){
      u16x4 o4;
#pragma unroll
      for (int jr = 0; jr < 4; jr++) o4[jr] = f2bf(acc[qh][d0][jr] * linv);
      *(u16x4*)(orow + d0 * 16 + lg * 4) = o4;
    }
  }
}

// ---------------- launch ----------------
extern "C" void kernel_launch(void* const* d_in, const int* in_sizes, int n_in,
                              void* d_out, int out_size, void* d_ws, size_t ws_size,
                              hipStream_t stream){
  const float* x  = (const float*)d_in[0];
  const float* rc = (const float*)d_in[1];
  const float* rs = (const float*)d_in[2];
  // d_in[3] = mask (causal tril; implemented in-kernel)
  const float* nw = (const float*)d_in[4];
  const float* wq = (const float*)d_in[5];
  const float* wk = (const float*)d_in[6];
  const float* wv = (const float*)d_in[7];
  const float* wo = (const float*)d_in[8];
  float* out = (float*)d_out;
  char* ws = (char*)d_ws;

  unsigned short* h_bf = (unsigned short*)(ws);                  // 16,777,216
  unsigned short* qkv  = (unsigned short*)(ws + 16777216ull);    // 2048*5120*2 = 20,971,520
  unsigned short* a_bf = (unsigned short*)(ws + 37748736ull);    // 16,777,216
  unsigned short* Wqkv = (unsigned short*)(ws + 54525952ull);    // 50,331,648
  unsigned short* Wo   = (unsigned short*)(ws + 104857600ull);   // 33,554,432
  unsigned short* vt   = (unsigned short*)(ws + 138412032ull);   // 8*128*2048*2 = 4,194,304 (end 142.6MB)

  cvt_f32_bf16<<<16384, 256, 0, stream>>>(wq, Wqkv, 4194304);
  cvt_f32_bf16<<<4096, 256, 0, stream>>>(wk, Wqkv + 16777216, 1048576);
  cvt_f32_bf16<<<4096, 256, 0, stream>>>(wv, Wqkv + 20971520, 1048576);
  cvt_f32_bf16<<<16384, 256, 0, stream>>>(wo, Wo, 4194304);
  rmsnorm_bf16<<<2048, 256, 0, stream>>>(x, nw, h_bf);
  gemm_bt<2><<<dim3(48, 16), 256, 0, stream>>>(h_bf, Wqkv, qkv, nullptr, vt, 4096, LDQ);
  rope_qk<<<dim3(10, 2048), 256, 0, stream>>>(qkv, rc, rs);
  attn_fwd<<<512, 256, 0, stream>>>(qkv, vt, a_bf);
  gemm_bt<1><<<dim3(32, 16), 256, 0, stream>>>(a_bf, Wo, out, x, nullptr, 4096, 4096);
}